// Round 1
// baseline (1120.931 us; speedup 1.0000x reference)
//
#include <hip/hip_runtime.h>
#include <hip/hip_bf16.h>

// Problem constants
constexpr int N_NODES = 50000;
constexpr int E_EDGES = 800000;
constexpr int ETOT    = E_EDGES + N_NODES;   // +self loops
constexpr int F_IN    = 128;
constexpr int H1 = 4, C1 = 32;               // layer1: 4 heads x 32 -> concat 128
constexpr int C2 = 40;                       // layer2: 1 head x 40
constexpr float NEG_SLOPE = 0.2f;

// ---------- helpers ----------
__device__ inline unsigned enc_f32(float f) {
    unsigned b = __float_as_uint(f);
    return (b & 0x80000000u) ? ~b : (b | 0x80000000u);
}
__device__ inline float dec_f32(unsigned u) {
    return (u & 0x80000000u) ? __uint_as_float(u & 0x7FFFFFFFu)
                             : __uint_as_float(~u);
}
__device__ inline void edge_sd(const int* __restrict__ ei, int e, int& s, int& d) {
    if (e < E_EDGES) { s = ei[e]; d = ei[E_EDGES + e]; }
    else             { s = e - E_EDGES; d = s; }
}

// ---------- GEMM1: h1[N,128] = x[N,128] @ W1[128,128] ----------
__global__ __launch_bounds__(256) void gemm1_kernel(const float* __restrict__ x,
                                                    const float* __restrict__ W,
                                                    float* __restrict__ h1) {
    __shared__ float wS[64 * 128];   // 32 KB (half of W at a time)
    __shared__ float xS[8 * 128];    // 4 KB
    int t = threadIdx.x;
    int row0 = blockIdx.x * 8;
    {   // load 8 x rows (1024 floats = 256 float4)
        int idx = t * 4;
        *(float4*)&xS[idx] = *(const float4*)&x[row0 * 128 + idx];
    }
    int rl   = t >> 5;          // 0..7 local row
    int col4 = (t & 31) * 4;    // 0..124
    float4 acc = make_float4(0.f, 0.f, 0.f, 0.f);
    for (int kk = 0; kk < 128; kk += 64) {
        __syncthreads();
        for (int i = 0; i < 8; ++i) {     // 8192 floats = 2048 float4 / 256 thr
            int idx = (i * 256 + t) * 4;
            *(float4*)&wS[idx] = *(const float4*)&W[kk * 128 + idx];
        }
        __syncthreads();
        for (int k = 0; k < 64; ++k) {
            float xv  = xS[rl * 128 + kk + k];
            float4 w4 = *(float4*)&wS[k * 128 + col4];
            acc.x += xv * w4.x; acc.y += xv * w4.y;
            acc.z += xv * w4.z; acc.w += xv * w4.w;
        }
    }
    *(float4*)&h1[(row0 + rl) * 128 + col4] = acc;
}

// ---------- attention logits layer1: als/ald [N,4] ----------
__global__ __launch_bounds__(256) void att1_kernel(const float* __restrict__ h1,
                                                   const float* __restrict__ as,
                                                   const float* __restrict__ ad,
                                                   float* __restrict__ als,
                                                   float* __restrict__ ald) {
    int gid = blockIdx.x * 256 + threadIdx.x;
    if (gid >= N_NODES * 128) return;
    int n = gid >> 7, c = gid & 127;
    float v = h1[gid];
    float s = v * as[c];
    float d = v * ad[c];
    #pragma unroll
    for (int off = 16; off >= 1; off >>= 1) {
        s += __shfl_xor(s, off);
        d += __shfl_xor(d, off);
    }
    if ((c & 31) == 0) {
        int h = c >> 5;
        als[n * 4 + h] = s;
        ald[n * 4 + h] = d;
    }
}

// ---------- attention logits layer2: als/ald [N] ----------
__global__ __launch_bounds__(256) void att2_kernel(const float* __restrict__ h2,
                                                   const float* __restrict__ as,
                                                   const float* __restrict__ ad,
                                                   float* __restrict__ als,
                                                   float* __restrict__ ald) {
    int t = threadIdx.x;
    int n = blockIdx.x * 4 + (t >> 6);
    if (n >= N_NODES) return;
    int lane = t & 63;
    float v = (lane < 40) ? h2[n * 40 + lane] : 0.f;
    float s = (lane < 40) ? v * as[lane] : 0.f;
    float d = (lane < 40) ? v * ad[lane] : 0.f;
    #pragma unroll
    for (int off = 32; off >= 1; off >>= 1) {
        s += __shfl_xor(s, off);
        d += __shfl_xor(d, off);
    }
    if (lane == 0) { als[n] = s; ald[n] = d; }
}

// ---------- edge pass 1: alpha = leaky(als[s]+ald[d]); segment max ----------
template <int H>
__global__ __launch_bounds__(256) void edge_alpha_max_kernel(const int* __restrict__ ei,
                                                             const float* __restrict__ als,
                                                             const float* __restrict__ ald,
                                                             float* __restrict__ alpha,
                                                             unsigned* __restrict__ m) {
    int e = blockIdx.x * 256 + threadIdx.x;
    if (e >= ETOT) return;
    int s, d; edge_sd(ei, e, s, d);
    #pragma unroll
    for (int h = 0; h < H; ++h) {
        float a = als[s * H + h] + ald[d * H + h];
        a = (a > 0.f) ? a : NEG_SLOPE * a;
        alpha[e * H + h] = a;
        atomicMax(&m[d * H + h], enc_f32(a));
    }
}

// ---------- edge pass 2: e = exp(alpha - m[d]); segment sum ----------
template <int H>
__global__ __launch_bounds__(256) void edge_exp_sum_kernel(const int* __restrict__ ei,
                                                           float* __restrict__ alpha,
                                                           const unsigned* __restrict__ m,
                                                           float* __restrict__ den) {
    int e = blockIdx.x * 256 + threadIdx.x;
    if (e >= ETOT) return;
    int d = (e < E_EDGES) ? ei[E_EDGES + e] : (e - E_EDGES);
    #pragma unroll
    for (int h = 0; h < H; ++h) {
        float ev = expf(alpha[e * H + h] - dec_f32(m[d * H + h]));
        alpha[e * H + h] = ev;
        atomicAdd(&den[d * H + h], ev);
    }
}

// ---------- edge pass 2.5: a = e / (den[d] + eps) ----------
template <int H>
__global__ __launch_bounds__(256) void edge_norm_kernel(const int* __restrict__ ei,
                                                        float* __restrict__ alpha,
                                                        const float* __restrict__ den) {
    int e = blockIdx.x * 256 + threadIdx.x;
    if (e >= ETOT) return;
    int d = (e < E_EDGES) ? ei[E_EDGES + e] : (e - E_EDGES);
    #pragma unroll
    for (int h = 0; h < H; ++h)
        alpha[e * H + h] = alpha[e * H + h] / (den[d * H + h] + 1e-16f);
}

// ---------- edge pass 3: scatter aggregate out[d] += h[s] * a ----------
template <int H, int C>
__global__ __launch_bounds__(256) void edge_aggregate_kernel(const int* __restrict__ ei,
                                                             const float* __restrict__ alpha,
                                                             const float* __restrict__ hsrc,
                                                             float* __restrict__ out) {
    int gid = blockIdx.x * 256 + threadIdx.x;
    if (gid >= ETOT * C) return;
    int e = gid / C, c = gid - e * C;
    int s, d; edge_sd(ei, e, s, d);
    int h = (H == 1) ? 0 : (c >> 5);   // C1=32 channels per head in layer1
    float a = alpha[e * H + h];
    atomicAdd(&out[d * C + c], hsrc[s * C + c] * a);
}

// ---------- bias + ELU (layer1 epilogue) ----------
__global__ __launch_bounds__(256) void bias_elu_kernel(float* __restrict__ out1,
                                                       const float* __restrict__ b) {
    int gid = blockIdx.x * 256 + threadIdx.x;
    if (gid >= N_NODES * 128) return;
    float v = out1[gid] + b[gid & 127];
    out1[gid] = (v > 0.f) ? v : (expf(v) - 1.f);
}

// ---------- GEMM2: h2[N,40] = out1[N,128] @ W2[128,40] ----------
__global__ __launch_bounds__(256) void gemm2_kernel(const float* __restrict__ x,
                                                    const float* __restrict__ W,
                                                    float* __restrict__ h2) {
    __shared__ float wS[128 * 40];   // 20 KB
    int t = threadIdx.x;
    for (int i = t; i < 128 * 40; i += 256) wS[i] = W[i];
    __syncthreads();
    int gid = blockIdx.x * 256 + t;
    if (gid >= N_NODES * 40) return;
    int n = gid / 40, col = gid - n * 40;
    const float* xr = x + n * 128;
    float acc = 0.f;
    #pragma unroll 4
    for (int k = 0; k < 128; ++k) acc += xr[k] * wS[k * 40 + col];
    h2[gid] = acc;
}

// ---------- final bias ----------
__global__ __launch_bounds__(256) void bias_out_kernel(float* __restrict__ out,
                                                       const float* __restrict__ b) {
    int gid = blockIdx.x * 256 + threadIdx.x;
    if (gid >= N_NODES * 40) return;
    int c = gid % 40;
    out[gid] += b[c];
}

// ---------- workspace layout (floats) ----------
// layer1 region:
constexpr size_t OFF_H1     = 0;                     // 6,400,000
constexpr size_t OFF_OUT1   = 6400000;               // 6,400,000
constexpr size_t OFF_ALS1   = 12800000;              // 200,000
constexpr size_t OFF_ALD1   = 13000000;              // 200,000
constexpr size_t OFF_M1     = 13200000;              // 200,000 (uint)
constexpr size_t OFF_DEN1   = 13400000;              // 200,000
constexpr size_t OFF_ALPHA1 = 13600000;              // 3,400,000 -> end 17,000,000
// layer2 region overlays h1 (dead after layer1 aggregation):
constexpr size_t OFF_H2     = 0;                     // 2,000,000
constexpr size_t OFF_ALS2   = 2000000;               // 50,000
constexpr size_t OFF_ALD2   = 2050000;               // 50,000
constexpr size_t OFF_M2     = 2100000;               // 50,000 (uint)
constexpr size_t OFF_DEN2   = 2150000;               // 50,000
constexpr size_t OFF_ALPHA2 = 2200000;               // 850,000 -> end 3,050,000
constexpr size_t WS_FLOATS  = 17000000;              // 68 MB

static inline int cdiv(long long a, int b) { return (int)((a + b - 1) / b); }

extern "C" void kernel_launch(void* const* d_in, const int* in_sizes, int n_in,
                              void* d_out, int out_size, void* d_ws, size_t ws_size,
                              hipStream_t stream) {
    const float* x   = (const float*)d_in[0];
    const int*   ei  = (const int*)  d_in[1];
    const float* W1  = (const float*)d_in[2];
    const float* as1 = (const float*)d_in[3];
    const float* ad1 = (const float*)d_in[4];
    const float* b1  = (const float*)d_in[5];
    const float* W2  = (const float*)d_in[6];
    const float* as2 = (const float*)d_in[7];
    const float* ad2 = (const float*)d_in[8];
    const float* b2  = (const float*)d_in[9];
    float* out = (float*)d_out;

    if (ws_size < WS_FLOATS * sizeof(float)) return;  // insufficient scratch

    float*    ws     = (float*)d_ws;
    float*    h1     = ws + OFF_H1;
    float*    out1   = ws + OFF_OUT1;
    float*    als1   = ws + OFF_ALS1;
    float*    ald1   = ws + OFF_ALD1;
    unsigned* m1     = (unsigned*)(ws + OFF_M1);
    float*    den1   = ws + OFF_DEN1;
    float*    alpha1 = ws + OFF_ALPHA1;
    float*    h2     = ws + OFF_H2;
    float*    als2   = ws + OFF_ALS2;
    float*    ald2   = ws + OFF_ALD2;
    unsigned* m2     = (unsigned*)(ws + OFF_M2);
    float*    den2   = ws + OFF_DEN2;
    float*    alpha2 = ws + OFF_ALPHA2;

    // ---- layer 1 ----
    hipMemsetAsync(out1, 0, (size_t)N_NODES * 128 * sizeof(float), stream);
    hipMemsetAsync(m1,   0, (size_t)N_NODES * 4 * sizeof(unsigned), stream);
    hipMemsetAsync(den1, 0, (size_t)N_NODES * 4 * sizeof(float), stream);

    gemm1_kernel<<<N_NODES / 8, 256, 0, stream>>>(x, W1, h1);
    att1_kernel<<<cdiv((long long)N_NODES * 128, 256), 256, 0, stream>>>(h1, as1, ad1, als1, ald1);

    int egrid = cdiv(ETOT, 256);
    edge_alpha_max_kernel<4><<<egrid, 256, 0, stream>>>(ei, als1, ald1, alpha1, m1);
    edge_exp_sum_kernel<4><<<egrid, 256, 0, stream>>>(ei, alpha1, m1, den1);
    edge_norm_kernel<4><<<egrid, 256, 0, stream>>>(ei, alpha1, den1);
    edge_aggregate_kernel<4, 128><<<cdiv((long long)ETOT * 128, 256), 256, 0, stream>>>(ei, alpha1, h1, out1);
    bias_elu_kernel<<<cdiv((long long)N_NODES * 128, 256), 256, 0, stream>>>(out1, b1);

    // ---- layer 2 (h1 region now dead; reuse) ----
    hipMemsetAsync(m2,   0, (size_t)N_NODES * sizeof(unsigned), stream);
    hipMemsetAsync(den2, 0, (size_t)N_NODES * sizeof(float), stream);
    hipMemsetAsync(out,  0, (size_t)N_NODES * 40 * sizeof(float), stream);

    gemm2_kernel<<<cdiv((long long)N_NODES * 40, 256), 256, 0, stream>>>(out1, W2, h2);
    att2_kernel<<<cdiv(N_NODES, 4), 256, 0, stream>>>(h2, as2, ad2, als2, ald2);

    edge_alpha_max_kernel<1><<<egrid, 256, 0, stream>>>(ei, als2, ald2, alpha2, m2);
    edge_exp_sum_kernel<1><<<egrid, 256, 0, stream>>>(ei, alpha2, m2, den2);
    edge_norm_kernel<1><<<egrid, 256, 0, stream>>>(ei, alpha2, den2);
    edge_aggregate_kernel<1, 40><<<cdiv((long long)ETOT * 40, 256), 256, 0, stream>>>(ei, alpha2, h2, out);
    bias_out_kernel<<<cdiv((long long)N_NODES * 40, 256), 256, 0, stream>>>(out, b2);
}

// Round 2
// 495.995 us; speedup vs baseline: 2.2600x; 2.2600x over previous
//
#include <hip/hip_runtime.h>
#include <hip/hip_bf16.h>
#include <math.h>

// Problem constants
constexpr int N_NODES = 50000;
constexpr int E_EDGES = 800000;
constexpr int ETOT    = E_EDGES + N_NODES;   // +self loops
constexpr int H1 = 4, C1 = 32;               // layer1: 4 heads x 32 -> concat 128
constexpr int C2 = 40;                       // layer2: 1 head x 40
constexpr float NEG_SLOPE = 0.2f;
constexpr float NEG_INF   = -3.0e38f;

static inline int cdiv(long long a, int b) { return (int)((a + b - 1) / b); }

__device__ inline void edge_sd(const int* __restrict__ ei, int e, int& s, int& d) {
    if (e < E_EDGES) { s = ei[e]; d = ei[E_EDGES + e]; }
    else             { s = e - E_EDGES; d = s; }
}
__device__ inline float leaky(float a) { return a > 0.f ? a : NEG_SLOPE * a; }

// ================= GEMM1: h1[N,128] = x[N,128] @ W1[128,128] =================
__global__ __launch_bounds__(256) void gemm1_kernel(const float* __restrict__ x,
                                                    const float* __restrict__ W,
                                                    float* __restrict__ h1) {
    __shared__ float wS[64 * 128];   // 32 KB (half of W at a time)
    __shared__ float xS[8 * 128];    // 4 KB
    int t = threadIdx.x;
    int row0 = blockIdx.x * 8;
    {
        int idx = t * 4;
        *(float4*)&xS[idx] = *(const float4*)&x[row0 * 128 + idx];
    }
    int rl   = t >> 5;
    int col4 = (t & 31) * 4;
    float4 acc = make_float4(0.f, 0.f, 0.f, 0.f);
    for (int kk = 0; kk < 128; kk += 64) {
        __syncthreads();
        for (int i = 0; i < 8; ++i) {
            int idx = (i * 256 + t) * 4;
            *(float4*)&wS[idx] = *(const float4*)&W[kk * 128 + idx];
        }
        __syncthreads();
        for (int k = 0; k < 64; ++k) {
            float xv  = xS[rl * 128 + kk + k];
            float4 w4 = *(float4*)&wS[k * 128 + col4];
            acc.x += xv * w4.x; acc.y += xv * w4.y;
            acc.z += xv * w4.z; acc.w += xv * w4.w;
        }
    }
    *(float4*)&h1[(row0 + rl) * 128 + col4] = acc;
}

// ============ attention logits layer1: als4/ald4 [N] (float4 per node) ============
__global__ __launch_bounds__(256) void att1_kernel(const float* __restrict__ h1,
                                                   const float* __restrict__ as,
                                                   const float* __restrict__ ad,
                                                   float* __restrict__ als,
                                                   float* __restrict__ ald) {
    int gid = blockIdx.x * 256 + threadIdx.x;
    if (gid >= N_NODES * 128) return;
    int n = gid >> 7, c = gid & 127;
    float v = h1[gid];
    float s = v * as[c];
    float d = v * ad[c];
    #pragma unroll
    for (int off = 16; off >= 1; off >>= 1) {
        s += __shfl_xor(s, off);
        d += __shfl_xor(d, off);
    }
    if ((c & 31) == 0) {
        int h = c >> 5;
        als[n * 4 + h] = s;
        ald[n * 4 + h] = d;
    }
}

// ============ attention logits layer2: als/ald [N] ============
__global__ __launch_bounds__(256) void att2_kernel(const float* __restrict__ h2,
                                                   const float* __restrict__ as,
                                                   const float* __restrict__ ad,
                                                   float* __restrict__ als,
                                                   float* __restrict__ ald) {
    int t = threadIdx.x;
    int n = blockIdx.x * 4 + (t >> 6);
    if (n >= N_NODES) return;
    int lane = t & 63;
    float v = (lane < 40) ? h2[n * 40 + lane] : 0.f;
    float s = (lane < 40) ? v * as[lane] : 0.f;
    float d = (lane < 40) ? v * ad[lane] : 0.f;
    #pragma unroll
    for (int off = 32; off >= 1; off >>= 1) {
        s += __shfl_xor(s, off);
        d += __shfl_xor(d, off);
    }
    if (lane == 0) { als[n] = s; ald[n] = d; }
}

// ================= CSR build =================
__global__ __launch_bounds__(256) void deg_count_kernel(const int* __restrict__ ei,
                                                        int* __restrict__ deg) {
    int e = blockIdx.x * 256 + threadIdx.x;
    if (e >= ETOT) return;
    int d = (e < E_EDGES) ? ei[E_EDGES + e] : (e - E_EDGES);
    atomicAdd(&deg[d], 1);
}

constexpr int SCAN_CHUNK = 512;
constexpr int SCAN_NBLK  = (N_NODES + SCAN_CHUNK - 1) / SCAN_CHUNK;   // 98

__global__ __launch_bounds__(256) void partial_sum_kernel(const int* __restrict__ deg,
                                                          int* __restrict__ part) {
    __shared__ int s[256];
    int b = blockIdx.x, t = threadIdx.x;
    int i0 = b * SCAN_CHUNK + t;
    int v = 0;
    if (i0 < N_NODES) v += deg[i0];
    if (i0 + 256 < N_NODES && (t + 256) < SCAN_CHUNK) v += deg[i0 + 256];
    s[t] = v; __syncthreads();
    for (int off = 128; off; off >>= 1) {
        if (t < off) s[t] += s[t + off];
        __syncthreads();
    }
    if (t == 0) part[b] = s[0];
}

__global__ void scan_part_kernel(int* __restrict__ part) {
    if (threadIdx.x == 0 && blockIdx.x == 0) {
        int acc = 0;
        for (int i = 0; i < SCAN_NBLK; ++i) { int v = part[i]; part[i] = acc; acc += v; }
    }
}

__global__ __launch_bounds__(256) void chunk_scan_kernel(const int* __restrict__ deg,
                                                         const int* __restrict__ part,
                                                         int* __restrict__ row) {
    __shared__ int s[256];
    int b = blockIdx.x, t = threadIdx.x;
    int base = b * SCAN_CHUNK;
    int i0 = base + 2 * t, i1 = base + 2 * t + 1;
    int a0 = (i0 < N_NODES) ? deg[i0] : 0;
    int a1 = (i1 < N_NODES) ? deg[i1] : 0;
    s[t] = a0 + a1;
    __syncthreads();
    // in-place Hillis-Steele inclusive scan over 256 thread-sums
    for (int off = 1; off < 256; off <<= 1) {
        int v = (t >= off) ? s[t - off] : 0;
        __syncthreads();
        s[t] += v;
        __syncthreads();
    }
    int excl = s[t] - (a0 + a1);
    int off0 = part[b] + excl;
    if (i0 < N_NODES) row[i0] = off0;
    if (i1 < N_NODES) row[i1] = off0 + a0;
    if (b == 0 && t == 0) row[N_NODES] = ETOT;
}

__global__ __launch_bounds__(256) void fill_csr_kernel(const int* __restrict__ ei,
                                                       int* __restrict__ cursor,
                                                       int* __restrict__ csr_src) {
    int e = blockIdx.x * 256 + threadIdx.x;
    if (e >= ETOT) return;
    int s, d; edge_sd(ei, e, s, d);
    int p = atomicAdd(&cursor[d], 1);
    csr_src[p] = s;
}

// ===== layer1 fused: per-dst softmax + gather-aggregate + bias + ELU =====
// one wave per destination node; lanes = channels {lane, lane+64}
__global__ __launch_bounds__(256) void agg1_kernel(const int* __restrict__ row,
                                                   const int* __restrict__ csr_src,
                                                   const float4* __restrict__ als4,
                                                   const float4* __restrict__ ald4,
                                                   const float* __restrict__ h1,
                                                   const float* __restrict__ b1,
                                                   float* __restrict__ out1) {
    int d = blockIdx.x * 4 + (threadIdx.x >> 6);
    if (d >= N_NODES) return;
    int lane  = threadIdx.x & 63;
    int start = row[d], end = row[d + 1];
    float4 aldd = ald4[d];

    // pass A: per-lane max of leaky logits (4 heads)
    float4 mx = make_float4(NEG_INF, NEG_INF, NEG_INF, NEG_INF);
    for (int j = start + lane; j < end; j += 64) {
        int s = csr_src[j];
        float4 a = als4[s];
        a.x = leaky(a.x + aldd.x); a.y = leaky(a.y + aldd.y);
        a.z = leaky(a.z + aldd.z); a.w = leaky(a.w + aldd.w);
        mx.x = fmaxf(mx.x, a.x); mx.y = fmaxf(mx.y, a.y);
        mx.z = fmaxf(mx.z, a.z); mx.w = fmaxf(mx.w, a.w);
    }
    #pragma unroll
    for (int off = 32; off >= 1; off >>= 1) {
        mx.x = fmaxf(mx.x, __shfl_xor(mx.x, off));
        mx.y = fmaxf(mx.y, __shfl_xor(mx.y, off));
        mx.z = fmaxf(mx.z, __shfl_xor(mx.z, off));
        mx.w = fmaxf(mx.w, __shfl_xor(mx.w, off));
    }

    // pass A2: sum of exp
    float4 sm = make_float4(0.f, 0.f, 0.f, 0.f);
    for (int j = start + lane; j < end; j += 64) {
        int s = csr_src[j];
        float4 a = als4[s];
        sm.x += __expf(leaky(a.x + aldd.x) - mx.x);
        sm.y += __expf(leaky(a.y + aldd.y) - mx.y);
        sm.z += __expf(leaky(a.z + aldd.z) - mx.z);
        sm.w += __expf(leaky(a.w + aldd.w) - mx.w);
    }
    #pragma unroll
    for (int off = 32; off >= 1; off >>= 1) {
        sm.x += __shfl_xor(sm.x, off);
        sm.y += __shfl_xor(sm.y, off);
        sm.z += __shfl_xor(sm.z, off);
        sm.w += __shfl_xor(sm.w, off);
    }
    float4 inv = make_float4(1.f / (sm.x + 1e-16f), 1.f / (sm.y + 1e-16f),
                             1.f / (sm.z + 1e-16f), 1.f / (sm.w + 1e-16f));

    // pass B: sequential gather-aggregate
    int  hsel = lane >> 5;    // 0 or 1
    float m0 = hsel ? mx.y  : mx.x,  m1 = hsel ? mx.w  : mx.z;
    float i0 = hsel ? inv.y : inv.x, i1 = hsel ? inv.w : inv.z;
    float acc0 = 0.f, acc1 = 0.f;
    for (int j = start; j < end; ++j) {
        int s = csr_src[j];
        float4 a = als4[s];
        float a0 = leaky((hsel ? a.y : a.x) + (hsel ? aldd.y : aldd.x));
        float a1 = leaky((hsel ? a.w : a.z) + (hsel ? aldd.w : aldd.z));
        float w0 = __expf(a0 - m0) * i0;
        float w1 = __expf(a1 - m1) * i1;
        const float* hr = h1 + (size_t)s * 128;
        acc0 += hr[lane]      * w0;
        acc1 += hr[64 + lane] * w1;
    }
    float v0 = acc0 + b1[lane];
    float v1 = acc1 + b1[64 + lane];
    out1[(size_t)d * 128 + lane]      = v0 > 0.f ? v0 : __expf(v0) - 1.f;
    out1[(size_t)d * 128 + 64 + lane] = v1 > 0.f ? v1 : __expf(v1) - 1.f;
}

// ===== layer2 fused: per-dst softmax + gather-aggregate + bias =====
__global__ __launch_bounds__(256) void agg2_kernel(const int* __restrict__ row,
                                                   const int* __restrict__ csr_src,
                                                   const float* __restrict__ als,
                                                   const float* __restrict__ ald,
                                                   const float* __restrict__ h2,
                                                   const float* __restrict__ b2,
                                                   float* __restrict__ out) {
    int d = blockIdx.x * 4 + (threadIdx.x >> 6);
    if (d >= N_NODES) return;
    int lane  = threadIdx.x & 63;
    int start = row[d], end = row[d + 1];
    float aldd = ald[d];

    float mx = NEG_INF;
    for (int j = start + lane; j < end; j += 64) {
        int s = csr_src[j];
        mx = fmaxf(mx, leaky(als[s] + aldd));
    }
    #pragma unroll
    for (int off = 32; off >= 1; off >>= 1) mx = fmaxf(mx, __shfl_xor(mx, off));

    float sm = 0.f;
    for (int j = start + lane; j < end; j += 64) {
        int s = csr_src[j];
        sm += __expf(leaky(als[s] + aldd) - mx);
    }
    #pragma unroll
    for (int off = 32; off >= 1; off >>= 1) sm += __shfl_xor(sm, off);
    float inv = 1.f / (sm + 1e-16f);

    float acc = 0.f;
    for (int j = start; j < end; ++j) {
        int s = csr_src[j];
        float w = __expf(leaky(als[s] + aldd) - mx) * inv;
        if (lane < 40) acc += h2[(size_t)s * 40 + lane] * w;
    }
    if (lane < 40) out[(size_t)d * 40 + lane] = acc + b2[lane];
}

// ================= GEMM2: h2[N,40] = out1[N,128] @ W2[128,40] =================
__global__ __launch_bounds__(256) void gemm2_kernel(const float* __restrict__ x,
                                                    const float* __restrict__ W,
                                                    float* __restrict__ h2) {
    __shared__ float wS[128 * 40];   // 20 KB
    int t = threadIdx.x;
    for (int i = t; i < 128 * 40; i += 256) wS[i] = W[i];
    __syncthreads();
    int gid = blockIdx.x * 256 + t;
    if (gid >= N_NODES * 40) return;
    int n = gid / 40, col = gid - n * 40;
    const float* xr = x + (size_t)n * 128;
    float acc = 0.f;
    #pragma unroll 4
    for (int k = 0; k < 128; ++k) acc += xr[k] * wS[k * 40 + col];
    h2[gid] = acc;
}

// ================= workspace layout (float-sized slots) =================
constexpr size_t OFF_H1     = 0;          // 6,400,000  (layer2: h2 overlays, 2,000,000)
constexpr size_t OFF_OUT1   = 6400000;    // 6,400,000
constexpr size_t OFF_ALS1   = 12800000;   // 200,000   (layer2: als2 overlays, 50,000)
constexpr size_t OFF_ALD1   = 13000000;   // 200,000   (layer2: ald2 overlays, 50,000)
constexpr size_t OFF_ROW    = 13200000;   // 50,004 (int)
constexpr size_t OFF_CURSOR = 13260000;   // 50,000 (int)
constexpr size_t OFF_DEG    = 13320000;   // 50,000 (int)
constexpr size_t OFF_PART   = 13380000;   // 128 (int)
constexpr size_t OFF_CSRC   = 13400000;   // 850,000 (int)
constexpr size_t WS_FLOATS  = 14250000;   // 57 MB

extern "C" void kernel_launch(void* const* d_in, const int* in_sizes, int n_in,
                              void* d_out, int out_size, void* d_ws, size_t ws_size,
                              hipStream_t stream) {
    const float* x   = (const float*)d_in[0];
    const int*   ei  = (const int*)  d_in[1];
    const float* W1  = (const float*)d_in[2];
    const float* as1 = (const float*)d_in[3];
    const float* ad1 = (const float*)d_in[4];
    const float* b1  = (const float*)d_in[5];
    const float* W2  = (const float*)d_in[6];
    const float* as2 = (const float*)d_in[7];
    const float* ad2 = (const float*)d_in[8];
    const float* b2  = (const float*)d_in[9];
    float* out = (float*)d_out;

    if (ws_size < WS_FLOATS * sizeof(float)) return;

    float* ws      = (float*)d_ws;
    float* h1      = ws + OFF_H1;
    float* out1    = ws + OFF_OUT1;
    float* als1    = ws + OFF_ALS1;
    float* ald1    = ws + OFF_ALD1;
    int*   rowp    = (int*)(ws + OFF_ROW);
    int*   cursor  = (int*)(ws + OFF_CURSOR);
    int*   deg     = (int*)(ws + OFF_DEG);
    int*   part    = (int*)(ws + OFF_PART);
    int*   csr_src = (int*)(ws + OFF_CSRC);
    float* h2      = ws + OFF_H1;     // overlays h1 (dead after agg1)
    float* als2    = ws + OFF_ALS1;   // overlays als1
    float* ald2    = ws + OFF_ALD1;   // overlays ald1

    int egrid = cdiv(ETOT, 256);

    // ---- CSR build (graph shared by both layers) ----
    hipMemsetAsync(deg, 0, (size_t)N_NODES * sizeof(int), stream);
    deg_count_kernel<<<egrid, 256, 0, stream>>>(ei, deg);
    partial_sum_kernel<<<SCAN_NBLK, 256, 0, stream>>>(deg, part);
    scan_part_kernel<<<1, 64, 0, stream>>>(part);
    chunk_scan_kernel<<<SCAN_NBLK, 256, 0, stream>>>(deg, part, rowp);
    hipMemcpyAsync(cursor, rowp, (size_t)N_NODES * sizeof(int),
                   hipMemcpyDeviceToDevice, stream);
    fill_csr_kernel<<<egrid, 256, 0, stream>>>(ei, cursor, csr_src);

    // ---- layer 1 ----
    gemm1_kernel<<<N_NODES / 8, 256, 0, stream>>>(x, W1, h1);
    att1_kernel<<<cdiv((long long)N_NODES * 128, 256), 256, 0, stream>>>(h1, as1, ad1, als1, ald1);
    agg1_kernel<<<cdiv(N_NODES, 4), 256, 0, stream>>>(rowp, csr_src,
                                                      (const float4*)als1, (const float4*)ald1,
                                                      h1, b1, out1);

    // ---- layer 2 ----
    gemm2_kernel<<<cdiv((long long)N_NODES * 40, 256), 256, 0, stream>>>(out1, W2, h2);
    att2_kernel<<<cdiv(N_NODES, 4), 256, 0, stream>>>(h2, as2, ad2, als2, ald2);
    agg2_kernel<<<cdiv(N_NODES, 4), 256, 0, stream>>>(rowp, csr_src, als2, ald2, h2, b2, out);
}

// Round 3
// 427.805 us; speedup vs baseline: 2.6202x; 1.1594x over previous
//
#include <hip/hip_runtime.h>
#include <hip/hip_bf16.h>
#include <math.h>

// Problem constants
constexpr int N_NODES = 50000;
constexpr int E_EDGES = 800000;
constexpr int ETOT    = E_EDGES + N_NODES;   // +self loops
constexpr float NEG_SLOPE = 0.2f;
constexpr float NEG_INF   = -3.0e38f;
constexpr int MAXD = 128;                    // LDS-cached edges per dst (fallback beyond)

static inline int cdiv(long long a, int b) { return (int)((a + b - 1) / b); }

__device__ inline float leaky(float a) { return a > 0.f ? a : NEG_SLOPE * a; }
__device__ inline float bf2f(unsigned short u) { return __uint_as_float((unsigned)u << 16); }
__device__ inline unsigned short f2bf(float f) {
    __hip_bfloat16 h = __float2bfloat16(f);
    return *reinterpret_cast<unsigned short*>(&h);
}
__device__ inline void edge_sd(const int* __restrict__ ei, int e, int& s, int& d) {
    if (e < E_EDGES) { s = ei[e]; d = ei[E_EDGES + e]; }
    else             { s = e - E_EDGES; d = s; }
}

// ====== GEMM1 + fused att1: h1b[N,128] bf16, als1/ald1[N,4] ======
__global__ __launch_bounds__(256) void gemm1_kernel(const float* __restrict__ x,
                                                    const float* __restrict__ W,
                                                    const float* __restrict__ as1,
                                                    const float* __restrict__ ad1,
                                                    unsigned short* __restrict__ h1b,
                                                    float* __restrict__ als,
                                                    float* __restrict__ ald) {
    __shared__ float wS[64 * 128];   // 32 KB
    __shared__ float xS[8 * 128];    // 4 KB
    int t = threadIdx.x;
    int row0 = blockIdx.x * 8;
    {
        int idx = t * 4;
        *(float4*)&xS[idx] = *(const float4*)&x[row0 * 128 + idx];
    }
    int rl   = t >> 5;          // local row 0..7
    int col4 = (t & 31) * 4;    // 0..124
    float4 acc = make_float4(0.f, 0.f, 0.f, 0.f);
    for (int kk = 0; kk < 128; kk += 64) {
        __syncthreads();
        for (int i = 0; i < 8; ++i) {
            int idx = (i * 256 + t) * 4;
            *(float4*)&wS[idx] = *(const float4*)&W[kk * 128 + idx];
        }
        __syncthreads();
        for (int k = 0; k < 64; ++k) {
            float xv  = xS[rl * 128 + kk + k];
            float4 w4 = *(float4*)&wS[k * 128 + col4];
            acc.x += xv * w4.x; acc.y += xv * w4.y;
            acc.z += xv * w4.z; acc.w += xv * w4.w;
        }
    }
    int n = row0 + rl;
    // bf16 store of h1 row
    uint2 packed;
    packed.x = ((unsigned)f2bf(acc.y) << 16) | f2bf(acc.x);
    packed.y = ((unsigned)f2bf(acc.w) << 16) | f2bf(acc.z);
    *(uint2*)&h1b[(size_t)n * 128 + col4] = packed;
    // fused attention logits: 8 consecutive lanes = one (row, head)
    float ps = acc.x * as1[col4] + acc.y * as1[col4 + 1] +
               acc.z * as1[col4 + 2] + acc.w * as1[col4 + 3];
    float pd = acc.x * ad1[col4] + acc.y * ad1[col4 + 1] +
               acc.z * ad1[col4 + 2] + acc.w * ad1[col4 + 3];
    #pragma unroll
    for (int off = 1; off <= 4; off <<= 1) {
        ps += __shfl_xor(ps, off);
        pd += __shfl_xor(pd, off);
    }
    if ((t & 7) == 0) {
        int head = (t & 31) >> 3;
        als[n * 4 + head] = ps;
        ald[n * 4 + head] = pd;
    }
}

// ============ attention logits layer2 (from bf16 h2) ============
__global__ __launch_bounds__(256) void att2_kernel(const unsigned short* __restrict__ h2b,
                                                   const float* __restrict__ as,
                                                   const float* __restrict__ ad,
                                                   float* __restrict__ als,
                                                   float* __restrict__ ald) {
    int t = threadIdx.x;
    int n = blockIdx.x * 4 + (t >> 6);
    if (n >= N_NODES) return;
    int lane = t & 63;
    float v = (lane < 40) ? bf2f(h2b[(size_t)n * 40 + lane]) : 0.f;
    float s = (lane < 40) ? v * as[lane] : 0.f;
    float d = (lane < 40) ? v * ad[lane] : 0.f;
    #pragma unroll
    for (int off = 32; off >= 1; off >>= 1) {
        s += __shfl_xor(s, off);
        d += __shfl_xor(d, off);
    }
    if (lane == 0) { als[n] = s; ald[n] = d; }
}

// ================= CSR build =================
__global__ __launch_bounds__(256) void deg_count_kernel(const int* __restrict__ ei,
                                                        int* __restrict__ deg) {
    int e = blockIdx.x * 256 + threadIdx.x;
    if (e >= ETOT) return;
    int d = (e < E_EDGES) ? ei[E_EDGES + e] : (e - E_EDGES);
    atomicAdd(&deg[d], 1);
}

constexpr int SCAN_CHUNK = 512;
constexpr int SCAN_NBLK  = (N_NODES + SCAN_CHUNK - 1) / SCAN_CHUNK;   // 98

__global__ __launch_bounds__(256) void partial_sum_kernel(const int* __restrict__ deg,
                                                          int* __restrict__ part) {
    __shared__ int s[256];
    int b = blockIdx.x, t = threadIdx.x;
    int i0 = b * SCAN_CHUNK + t;
    int v = 0;
    if (i0 < N_NODES) v += deg[i0];
    if (i0 + 256 < N_NODES && (t + 256) < SCAN_CHUNK) v += deg[i0 + 256];
    s[t] = v; __syncthreads();
    for (int off = 128; off; off >>= 1) {
        if (t < off) s[t] += s[t + off];
        __syncthreads();
    }
    if (t == 0) part[b] = s[0];
}

__global__ void scan_part_kernel(int* __restrict__ part) {
    if (threadIdx.x == 0 && blockIdx.x == 0) {
        int acc = 0;
        for (int i = 0; i < SCAN_NBLK; ++i) { int v = part[i]; part[i] = acc; acc += v; }
    }
}

__global__ __launch_bounds__(256) void chunk_scan_kernel(const int* __restrict__ deg,
                                                         const int* __restrict__ part,
                                                         int* __restrict__ row) {
    __shared__ int s[256];
    int b = blockIdx.x, t = threadIdx.x;
    int base = b * SCAN_CHUNK;
    int i0 = base + 2 * t, i1 = base + 2 * t + 1;
    int a0 = (i0 < N_NODES) ? deg[i0] : 0;
    int a1 = (i1 < N_NODES) ? deg[i1] : 0;
    s[t] = a0 + a1;
    __syncthreads();
    for (int off = 1; off < 256; off <<= 1) {
        int v = (t >= off) ? s[t - off] : 0;
        __syncthreads();
        s[t] += v;
        __syncthreads();
    }
    int excl = s[t] - (a0 + a1);
    int off0 = part[b] + excl;
    if (i0 < N_NODES) row[i0] = off0;
    if (i1 < N_NODES) row[i1] = off0 + a0;
    if (b == 0 && t == 0) row[N_NODES] = ETOT;
}

__global__ __launch_bounds__(256) void fill_csr_kernel(const int* __restrict__ ei,
                                                       int* __restrict__ cursor,
                                                       int* __restrict__ csr_src) {
    int e = blockIdx.x * 256 + threadIdx.x;
    if (e >= ETOT) return;
    int s, d; edge_sd(ei, e, s, d);
    int p = atomicAdd(&cursor[d], 1);
    csr_src[p] = s;
}

// ===== layer1 fused: per-dst softmax (LDS-cached weights) + bf16 gather + bias + ELU =====
// one wave per dst; pass B: lane l <-> channels {2l, 2l+1}, head = l>>4
__global__ __launch_bounds__(256) void agg1_kernel(const int* __restrict__ row,
                                                   const int* __restrict__ csr_src,
                                                   const float4* __restrict__ als4,
                                                   const float4* __restrict__ ald4,
                                                   const unsigned short* __restrict__ h1b,
                                                   const float* __restrict__ b1,
                                                   float* __restrict__ out1) {
    __shared__ float wbuf[4][MAXD * 4] __attribute__((aligned(16)));
    int wv   = threadIdx.x >> 6;
    int lane = threadIdx.x & 63;
    int d    = blockIdx.x * 4 + wv;           // grid exactly covers N: no early return
    int start = row[d], end = row[d + 1], deg = end - start;
    float4 aldd = ald4[d];

    // pass A: alpha -> LDS, per-lane max
    float4 mx = make_float4(NEG_INF, NEG_INF, NEG_INF, NEG_INF);
    for (int j = lane; j < deg; j += 64) {
        int s = csr_src[start + j];
        float4 a = als4[s];
        a.x = leaky(a.x + aldd.x); a.y = leaky(a.y + aldd.y);
        a.z = leaky(a.z + aldd.z); a.w = leaky(a.w + aldd.w);
        if (j < MAXD) *(float4*)&wbuf[wv][j * 4] = a;
        mx.x = fmaxf(mx.x, a.x); mx.y = fmaxf(mx.y, a.y);
        mx.z = fmaxf(mx.z, a.z); mx.w = fmaxf(mx.w, a.w);
    }
    #pragma unroll
    for (int off = 32; off >= 1; off >>= 1) {
        mx.x = fmaxf(mx.x, __shfl_xor(mx.x, off));
        mx.y = fmaxf(mx.y, __shfl_xor(mx.y, off));
        mx.z = fmaxf(mx.z, __shfl_xor(mx.z, off));
        mx.w = fmaxf(mx.w, __shfl_xor(mx.w, off));
    }
    __syncthreads();

    // pass A2: exp in LDS, per-lane sum
    float4 sm = make_float4(0.f, 0.f, 0.f, 0.f);
    for (int j = lane; j < deg; j += 64) {
        float4 a;
        if (j < MAXD) a = *(float4*)&wbuf[wv][j * 4];
        else {
            int s = csr_src[start + j];
            float4 t = als4[s];
            a.x = leaky(t.x + aldd.x); a.y = leaky(t.y + aldd.y);
            a.z = leaky(t.z + aldd.z); a.w = leaky(t.w + aldd.w);
        }
        float4 e;
        e.x = __expf(a.x - mx.x); e.y = __expf(a.y - mx.y);
        e.z = __expf(a.z - mx.z); e.w = __expf(a.w - mx.w);
        if (j < MAXD) *(float4*)&wbuf[wv][j * 4] = e;
        sm.x += e.x; sm.y += e.y; sm.z += e.z; sm.w += e.w;
    }
    #pragma unroll
    for (int off = 32; off >= 1; off >>= 1) {
        sm.x += __shfl_xor(sm.x, off);
        sm.y += __shfl_xor(sm.y, off);
        sm.z += __shfl_xor(sm.z, off);
        sm.w += __shfl_xor(sm.w, off);
    }
    __syncthreads();

    int head = lane >> 4;
    float m_h = (head & 2) ? ((head & 1) ? mx.w : mx.z) : ((head & 1) ? mx.y : mx.x);
    float s_h = (head & 2) ? ((head & 1) ? sm.w : sm.z) : ((head & 1) ? sm.y : sm.x);
    float inv_h = 1.f / (s_h + 1e-16f);

    // pass B: gather-aggregate (bf16 rows, cached weights), unrolled x2
    float acc0 = 0.f, acc1 = 0.f;
    int j = 0;
    for (; j + 1 < deg; j += 2) {
        int s0 = csr_src[start + j];
        int s1 = csr_src[start + j + 1];
        float e0, e1;
        if (j < MAXD)     e0 = wbuf[wv][j * 4 + head];
        else { float4 a = als4[s0];
               float ah = (head & 2) ? ((head & 1) ? a.w : a.z) : ((head & 1) ? a.y : a.x);
               float dh = (head & 2) ? ((head & 1) ? aldd.w : aldd.z) : ((head & 1) ? aldd.y : aldd.x);
               e0 = __expf(leaky(ah + dh) - m_h); }
        if (j + 1 < MAXD) e1 = wbuf[wv][(j + 1) * 4 + head];
        else { float4 a = als4[s1];
               float ah = (head & 2) ? ((head & 1) ? a.w : a.z) : ((head & 1) ? a.y : a.x);
               float dh = (head & 2) ? ((head & 1) ? aldd.w : aldd.z) : ((head & 1) ? aldd.y : aldd.x);
               e1 = __expf(leaky(ah + dh) - m_h); }
        float w0 = e0 * inv_h, w1 = e1 * inv_h;
        unsigned hv0 = *(const unsigned*)(h1b + ((size_t)s0 << 7) + 2 * lane);
        unsigned hv1 = *(const unsigned*)(h1b + ((size_t)s1 << 7) + 2 * lane);
        acc0 += __uint_as_float(hv0 << 16)          * w0;
        acc1 += __uint_as_float(hv0 & 0xffff0000u)  * w0;
        acc0 += __uint_as_float(hv1 << 16)          * w1;
        acc1 += __uint_as_float(hv1 & 0xffff0000u)  * w1;
    }
    if (j < deg) {
        int s0 = csr_src[start + j];
        float e0;
        if (j < MAXD) e0 = wbuf[wv][j * 4 + head];
        else { float4 a = als4[s0];
               float ah = (head & 2) ? ((head & 1) ? a.w : a.z) : ((head & 1) ? a.y : a.x);
               float dh = (head & 2) ? ((head & 1) ? aldd.w : aldd.z) : ((head & 1) ? aldd.y : aldd.x);
               e0 = __expf(leaky(ah + dh) - m_h); }
        float w0 = e0 * inv_h;
        unsigned hv0 = *(const unsigned*)(h1b + ((size_t)s0 << 7) + 2 * lane);
        acc0 += __uint_as_float(hv0 << 16)         * w0;
        acc1 += __uint_as_float(hv0 & 0xffff0000u) * w0;
    }
    float v0 = acc0 + b1[2 * lane];
    float v1 = acc1 + b1[2 * lane + 1];
    v0 = v0 > 0.f ? v0 : __expf(v0) - 1.f;
    v1 = v1 > 0.f ? v1 : __expf(v1) - 1.f;
    float2 o = make_float2(v0, v1);
    *(float2*)&out1[(size_t)d * 128 + 2 * lane] = o;
}

// ===== layer2 fused: per-dst softmax (LDS weights) + bf16 gather + bias =====
__global__ __launch_bounds__(256) void agg2_kernel(const int* __restrict__ row,
                                                   const int* __restrict__ csr_src,
                                                   const float* __restrict__ als,
                                                   const float* __restrict__ ald,
                                                   const unsigned short* __restrict__ h2b,
                                                   const float* __restrict__ b2,
                                                   float* __restrict__ out) {
    __shared__ float wbuf[4][MAXD];
    int wv   = threadIdx.x >> 6;
    int lane = threadIdx.x & 63;
    int d    = blockIdx.x * 4 + wv;
    int start = row[d], end = row[d + 1], deg = end - start;
    float aldd = ald[d];

    float mx = NEG_INF;
    for (int j = lane; j < deg; j += 64) {
        int s = csr_src[start + j];
        float a = leaky(als[s] + aldd);
        if (j < MAXD) wbuf[wv][j] = a;
        mx = fmaxf(mx, a);
    }
    #pragma unroll
    for (int off = 32; off >= 1; off >>= 1) mx = fmaxf(mx, __shfl_xor(mx, off));
    __syncthreads();

    float sm = 0.f;
    for (int j = lane; j < deg; j += 64) {
        float a;
        if (j < MAXD) a = wbuf[wv][j];
        else { int s = csr_src[start + j]; a = leaky(als[s] + aldd); }
        float e = __expf(a - mx);
        if (j < MAXD) wbuf[wv][j] = e;
        sm += e;
    }
    #pragma unroll
    for (int off = 32; off >= 1; off >>= 1) sm += __shfl_xor(sm, off);
    __syncthreads();
    float inv = 1.f / (sm + 1e-16f);

    float acc0 = 0.f, acc1 = 0.f;
    for (int j = 0; j < deg; ++j) {
        int s = csr_src[start + j];
        float e;
        if (j < MAXD) e = wbuf[wv][j];
        else e = __expf(leaky(als[s] + aldd) - mx);
        float w = e * inv;
        if (lane < 20) {
            unsigned hv = *(const unsigned*)(h2b + (size_t)s * 40 + 2 * lane);
            acc0 += __uint_as_float(hv << 16)         * w;
            acc1 += __uint_as_float(hv & 0xffff0000u) * w;
        }
    }
    if (lane < 20) {
        float2 o = make_float2(acc0 + b2[2 * lane], acc1 + b2[2 * lane + 1]);
        *(float2*)&out[(size_t)d * 40 + 2 * lane] = o;
    }
}

// ================= GEMM2: h2b[N,40] bf16 = out1[N,128] @ W2[128,40] =================
__global__ __launch_bounds__(256) void gemm2_kernel(const float* __restrict__ x,
                                                    const float* __restrict__ W,
                                                    unsigned short* __restrict__ h2b) {
    __shared__ float wS[128 * 40];   // 20 KB
    int t = threadIdx.x;
    for (int i = t; i < 128 * 40; i += 256) wS[i] = W[i];
    __syncthreads();
    int gid = blockIdx.x * 256 + t;
    if (gid >= N_NODES * 40) return;
    int n = gid / 40, col = gid - n * 40;
    const float* xr = x + (size_t)n * 128;
    float acc = 0.f;
    #pragma unroll 4
    for (int k = 0; k < 128; ++k) acc += xr[k] * wS[k * 40 + col];
    h2b[gid] = f2bf(acc);
}

// ================= workspace layout (float-sized slots) =================
constexpr size_t OFF_H1B    = 0;          // 3,200,000 slots (bf16 x 6.4M); h2b overlays after agg1
constexpr size_t OFF_OUT1   = 3200000;    // 6,400,000
constexpr size_t OFF_ALS1   = 9600000;    // 200,000 (als2 overlays)
constexpr size_t OFF_ALD1   = 9800000;    // 200,000 (ald2 overlays)
constexpr size_t OFF_ROW    = 10000000;   // 50,001 ints
constexpr size_t OFF_CURSOR = 10060000;   // 50,000 ints
constexpr size_t OFF_DEG    = 10120000;   // 50,000 ints
constexpr size_t OFF_PART   = 10180000;   // 128 ints
constexpr size_t OFF_CSRC   = 10200000;   // 850,000 ints
constexpr size_t WS_FLOATS  = 11050000;   // 44.2 MB

extern "C" void kernel_launch(void* const* d_in, const int* in_sizes, int n_in,
                              void* d_out, int out_size, void* d_ws, size_t ws_size,
                              hipStream_t stream) {
    const float* x   = (const float*)d_in[0];
    const int*   ei  = (const int*)  d_in[1];
    const float* W1  = (const float*)d_in[2];
    const float* as1 = (const float*)d_in[3];
    const float* ad1 = (const float*)d_in[4];
    const float* b1  = (const float*)d_in[5];
    const float* W2  = (const float*)d_in[6];
    const float* as2 = (const float*)d_in[7];
    const float* ad2 = (const float*)d_in[8];
    const float* b2  = (const float*)d_in[9];
    float* out = (float*)d_out;

    if (ws_size < WS_FLOATS * sizeof(float)) return;

    float* ws = (float*)d_ws;
    unsigned short* h1b = (unsigned short*)(ws + OFF_H1B);
    unsigned short* h2b = (unsigned short*)(ws + OFF_H1B);   // overlay, h1b dead after agg1
    float* out1    = ws + OFF_OUT1;
    float* als1    = ws + OFF_ALS1;
    float* ald1    = ws + OFF_ALD1;
    float* als2    = ws + OFF_ALS1;   // overlay
    float* ald2    = ws + OFF_ALD1;   // overlay
    int*   rowp    = (int*)(ws + OFF_ROW);
    int*   cursor  = (int*)(ws + OFF_CURSOR);
    int*   deg     = (int*)(ws + OFF_DEG);
    int*   part    = (int*)(ws + OFF_PART);
    int*   csr_src = (int*)(ws + OFF_CSRC);

    int egrid = cdiv(ETOT, 256);

    // ---- CSR build (shared by both layers) ----
    hipMemsetAsync(deg, 0, (size_t)N_NODES * sizeof(int), stream);
    deg_count_kernel<<<egrid, 256, 0, stream>>>(ei, deg);
    partial_sum_kernel<<<SCAN_NBLK, 256, 0, stream>>>(deg, part);
    scan_part_kernel<<<1, 64, 0, stream>>>(part);
    chunk_scan_kernel<<<SCAN_NBLK, 256, 0, stream>>>(deg, part, rowp);
    hipMemcpyAsync(cursor, rowp, (size_t)N_NODES * sizeof(int),
                   hipMemcpyDeviceToDevice, stream);
    fill_csr_kernel<<<egrid, 256, 0, stream>>>(ei, cursor, csr_src);

    // ---- layer 1 ----
    gemm1_kernel<<<N_NODES / 8, 256, 0, stream>>>(x, W1, as1, ad1, h1b, als1, ald1);
    agg1_kernel<<<N_NODES / 4, 256, 0, stream>>>(rowp, csr_src,
                                                 (const float4*)als1, (const float4*)ald1,
                                                 h1b, b1, out1);

    // ---- layer 2 ----
    gemm2_kernel<<<cdiv((long long)N_NODES * 40, 256), 256, 0, stream>>>(out1, W2, h2b);
    att2_kernel<<<cdiv(N_NODES, 4), 256, 0, stream>>>(h2b, as2, ad2, als2, ald2);
    agg2_kernel<<<N_NODES / 4, 256, 0, stream>>>(rowp, csr_src, als2, ald2, h2b, b2, out);
}

// Round 4
// 355.857 us; speedup vs baseline: 3.1499x; 1.2022x over previous
//
#include <hip/hip_runtime.h>
#include <hip/hip_bf16.h>
#include <math.h>

// Problem constants
constexpr int N_NODES = 50000;
constexpr int E_EDGES = 800000;
constexpr int ETOT    = E_EDGES + N_NODES;   // +self loops
constexpr float NEG_SLOPE = 0.2f;
constexpr float NEG_INF   = -3.0e38f;
constexpr int MAXD = 128;                    // LDS-cached edges per dst (fallback beyond)

static inline int cdiv(long long a, int b) { return (int)((a + b - 1) / b); }

__device__ inline float leaky(float a) { return a > 0.f ? a : NEG_SLOPE * a; }
__device__ inline float bf2f(unsigned short u) { return __uint_as_float((unsigned)u << 16); }
__device__ inline unsigned short f2bf(float f) {
    __hip_bfloat16 h = __float2bfloat16(f);
    return *reinterpret_cast<unsigned short*>(&h);
}
__device__ inline void edge_sd(const int* __restrict__ ei, int e, int& s, int& d) {
    if (e < E_EDGES) { s = ei[e]; d = ei[E_EDGES + e]; }
    else             { s = e - E_EDGES; d = s; }
}

// ====== GEMM1 + fused att1: h1b[N,128] bf16, als1/ald1[N,4] ======
// 32 rows/block, 4 rows/thread (register-blocked), 256 threads
__global__ __launch_bounds__(256) void gemm1_kernel(const float* __restrict__ x,
                                                    const float* __restrict__ W,
                                                    const float* __restrict__ as1,
                                                    const float* __restrict__ ad1,
                                                    unsigned short* __restrict__ h1b,
                                                    float* __restrict__ als,
                                                    float* __restrict__ ald) {
    __shared__ float wS[64 * 128];   // 32 KB
    __shared__ float xS[32 * 128];   // 16 KB
    int t = threadIdx.x;
    int row0 = blockIdx.x * 32;
    // stage 32 x rows (1024 float4, 4 per thread), zero-pad OOB rows
    #pragma unroll
    for (int i = 0; i < 4; ++i) {
        int fi = i * 256 + t;
        int r = fi >> 5, c4 = (fi & 31) * 4;
        int gr = row0 + r;
        float4 v = make_float4(0.f, 0.f, 0.f, 0.f);
        if (gr < N_NODES) v = *(const float4*)&x[(size_t)gr * 128 + c4];
        *(float4*)&xS[r * 128 + c4] = v;
    }
    int rg   = t >> 5;          // row group 0..7 -> rows rg*4..rg*4+3
    int col4 = (t & 31) * 4;    // 0..124
    float4 a0 = make_float4(0.f,0.f,0.f,0.f), a1 = a0, a2 = a0, a3 = a0;
    for (int kk = 0; kk < 128; kk += 64) {
        __syncthreads();
        for (int i = 0; i < 8; ++i) {
            int idx = (i * 256 + t) * 4;
            *(float4*)&wS[idx] = *(const float4*)&W[kk * 128 + idx];
        }
        __syncthreads();
        for (int k = 0; k < 64; ++k) {
            float4 w4 = *(float4*)&wS[k * 128 + col4];
            float x0 = xS[(rg * 4 + 0) * 128 + kk + k];
            float x1 = xS[(rg * 4 + 1) * 128 + kk + k];
            float x2 = xS[(rg * 4 + 2) * 128 + kk + k];
            float x3 = xS[(rg * 4 + 3) * 128 + kk + k];
            a0.x += x0 * w4.x; a0.y += x0 * w4.y; a0.z += x0 * w4.z; a0.w += x0 * w4.w;
            a1.x += x1 * w4.x; a1.y += x1 * w4.y; a1.z += x1 * w4.z; a1.w += x1 * w4.w;
            a2.x += x2 * w4.x; a2.y += x2 * w4.y; a2.z += x2 * w4.z; a2.w += x2 * w4.w;
            a3.x += x3 * w4.x; a3.y += x3 * w4.y; a3.z += x3 * w4.z; a3.w += x3 * w4.w;
        }
    }
    float s0 = as1[col4], s1 = as1[col4 + 1], s2 = as1[col4 + 2], s3 = as1[col4 + 3];
    float d0 = ad1[col4], d1 = ad1[col4 + 1], d2 = ad1[col4 + 2], d3 = ad1[col4 + 3];
    #pragma unroll
    for (int r = 0; r < 4; ++r) {
        float4 a = (r == 0) ? a0 : (r == 1) ? a1 : (r == 2) ? a2 : a3;
        int n = row0 + rg * 4 + r;
        float ps = a.x * s0 + a.y * s1 + a.z * s2 + a.w * s3;
        float pd = a.x * d0 + a.y * d1 + a.z * d2 + a.w * d3;
        #pragma unroll
        for (int off = 1; off <= 4; off <<= 1) {
            ps += __shfl_xor(ps, off);
            pd += __shfl_xor(pd, off);
        }
        if (n < N_NODES) {
            uint2 packed;
            packed.x = ((unsigned)f2bf(a.y) << 16) | f2bf(a.x);
            packed.y = ((unsigned)f2bf(a.w) << 16) | f2bf(a.z);
            *(uint2*)&h1b[(size_t)n * 128 + col4] = packed;
            if ((t & 7) == 0) {
                int head = (t & 31) >> 3;
                als[n * 4 + head] = ps;
                ald[n * 4 + head] = pd;
            }
        }
    }
}

// ============ attention logits layer2 (from bf16 h2) ============
__global__ __launch_bounds__(256) void att2_kernel(const unsigned short* __restrict__ h2b,
                                                   const float* __restrict__ as,
                                                   const float* __restrict__ ad,
                                                   float* __restrict__ als,
                                                   float* __restrict__ ald) {
    int t = threadIdx.x;
    int n = blockIdx.x * 4 + (t >> 6);
    if (n >= N_NODES) return;
    int lane = t & 63;
    float v = (lane < 40) ? bf2f(h2b[(size_t)n * 40 + lane]) : 0.f;
    float s = (lane < 40) ? v * as[lane] : 0.f;
    float d = (lane < 40) ? v * ad[lane] : 0.f;
    #pragma unroll
    for (int off = 32; off >= 1; off >>= 1) {
        s += __shfl_xor(s, off);
        d += __shfl_xor(d, off);
    }
    if (lane == 0) { als[n] = s; ald[n] = d; }
}

// ================= CSR build =================
__global__ __launch_bounds__(256) void deg_count_kernel(const int* __restrict__ ei,
                                                        int* __restrict__ deg) {
    int e = blockIdx.x * 256 + threadIdx.x;
    if (e >= ETOT) return;
    int d = (e < E_EDGES) ? ei[E_EDGES + e] : (e - E_EDGES);
    atomicAdd(&deg[d], 1);
}

constexpr int SCAN_CHUNK = 512;
constexpr int SCAN_NBLK  = (N_NODES + SCAN_CHUNK - 1) / SCAN_CHUNK;   // 98

__global__ __launch_bounds__(256) void partial_sum_kernel(const int* __restrict__ deg,
                                                          int* __restrict__ part) {
    __shared__ int s[256];
    int b = blockIdx.x, t = threadIdx.x;
    int i0 = b * SCAN_CHUNK + t;
    int v = 0;
    if (i0 < N_NODES) v += deg[i0];
    if (i0 + 256 < N_NODES && (t + 256) < SCAN_CHUNK) v += deg[i0 + 256];
    s[t] = v; __syncthreads();
    for (int off = 128; off; off >>= 1) {
        if (t < off) s[t] += s[t + off];
        __syncthreads();
    }
    if (t == 0) part[b] = s[0];
}

__global__ void scan_part_kernel(int* __restrict__ part) {
    if (threadIdx.x == 0 && blockIdx.x == 0) {
        int acc = 0;
        for (int i = 0; i < SCAN_NBLK; ++i) { int v = part[i]; part[i] = acc; acc += v; }
    }
}

__global__ __launch_bounds__(256) void chunk_scan_kernel(const int* __restrict__ deg,
                                                         const int* __restrict__ part,
                                                         int* __restrict__ row,
                                                         int* __restrict__ cursor) {
    __shared__ int s[256];
    int b = blockIdx.x, t = threadIdx.x;
    int base = b * SCAN_CHUNK;
    int i0 = base + 2 * t, i1 = base + 2 * t + 1;
    int a0 = (i0 < N_NODES) ? deg[i0] : 0;
    int a1 = (i1 < N_NODES) ? deg[i1] : 0;
    s[t] = a0 + a1;
    __syncthreads();
    for (int off = 1; off < 256; off <<= 1) {
        int v = (t >= off) ? s[t - off] : 0;
        __syncthreads();
        s[t] += v;
        __syncthreads();
    }
    int excl = s[t] - (a0 + a1);
    int off0 = part[b] + excl;
    if (i0 < N_NODES) { row[i0] = off0;      cursor[i0] = off0; }
    if (i1 < N_NODES) { row[i1] = off0 + a0; cursor[i1] = off0 + a0; }
    if (b == 0 && t == 0) row[N_NODES] = ETOT;
}

__global__ __launch_bounds__(256) void fill_csr_kernel(const int* __restrict__ ei,
                                                       int* __restrict__ cursor,
                                                       int* __restrict__ csr_src) {
    int e = blockIdx.x * 256 + threadIdx.x;
    if (e >= ETOT) return;
    int s, d; edge_sd(ei, e, s, d);
    int p = atomicAdd(&cursor[d], 1);
    csr_src[p] = s;
}

// ===== layer1 fused: per-dst softmax (LDS-cached weights) + bf16 gather + bias + ELU =====
// one wave per dst; pass B: lane l <-> channels {2l, 2l+1}, head = l>>4
__global__ __launch_bounds__(256) void agg1_kernel(const int* __restrict__ row,
                                                   const int* __restrict__ csr_src,
                                                   const float4* __restrict__ als4,
                                                   const float4* __restrict__ ald4,
                                                   const unsigned short* __restrict__ h1b,
                                                   const float* __restrict__ b1,
                                                   float* __restrict__ out1) {
    __shared__ float wbuf[4][MAXD * 4] __attribute__((aligned(16)));
    int wv   = threadIdx.x >> 6;
    int lane = threadIdx.x & 63;
    int d    = blockIdx.x * 4 + wv;           // grid exactly covers N: no early return
    int start = row[d], end = row[d + 1], deg = end - start;
    float4 aldd = ald4[d];

    // pass A: alpha -> LDS, per-lane max
    float4 mx = make_float4(NEG_INF, NEG_INF, NEG_INF, NEG_INF);
    for (int j = lane; j < deg; j += 64) {
        int s = csr_src[start + j];
        float4 a = als4[s];
        a.x = leaky(a.x + aldd.x); a.y = leaky(a.y + aldd.y);
        a.z = leaky(a.z + aldd.z); a.w = leaky(a.w + aldd.w);
        if (j < MAXD) *(float4*)&wbuf[wv][j * 4] = a;
        mx.x = fmaxf(mx.x, a.x); mx.y = fmaxf(mx.y, a.y);
        mx.z = fmaxf(mx.z, a.z); mx.w = fmaxf(mx.w, a.w);
    }
    #pragma unroll
    for (int off = 32; off >= 1; off >>= 1) {
        mx.x = fmaxf(mx.x, __shfl_xor(mx.x, off));
        mx.y = fmaxf(mx.y, __shfl_xor(mx.y, off));
        mx.z = fmaxf(mx.z, __shfl_xor(mx.z, off));
        mx.w = fmaxf(mx.w, __shfl_xor(mx.w, off));
    }
    __syncthreads();

    // pass A2: exp in LDS, per-lane sum
    float4 sm = make_float4(0.f, 0.f, 0.f, 0.f);
    for (int j = lane; j < deg; j += 64) {
        float4 a;
        if (j < MAXD) a = *(float4*)&wbuf[wv][j * 4];
        else {
            int s = csr_src[start + j];
            float4 t = als4[s];
            a.x = leaky(t.x + aldd.x); a.y = leaky(t.y + aldd.y);
            a.z = leaky(t.z + aldd.z); a.w = leaky(t.w + aldd.w);
        }
        float4 e;
        e.x = __expf(a.x - mx.x); e.y = __expf(a.y - mx.y);
        e.z = __expf(a.z - mx.z); e.w = __expf(a.w - mx.w);
        if (j < MAXD) *(float4*)&wbuf[wv][j * 4] = e;
        sm.x += e.x; sm.y += e.y; sm.z += e.z; sm.w += e.w;
    }
    #pragma unroll
    for (int off = 32; off >= 1; off >>= 1) {
        sm.x += __shfl_xor(sm.x, off);
        sm.y += __shfl_xor(sm.y, off);
        sm.z += __shfl_xor(sm.z, off);
        sm.w += __shfl_xor(sm.w, off);
    }
    __syncthreads();

    int head = lane >> 4;
    float m_h = (head & 2) ? ((head & 1) ? mx.w : mx.z) : ((head & 1) ? mx.y : mx.x);
    float s_h = (head & 2) ? ((head & 1) ? sm.w : sm.z) : ((head & 1) ? sm.y : sm.x);
    float inv_h = 1.f / (s_h + 1e-16f);

    // pass B: gather-aggregate (bf16 rows, cached weights), unrolled x2
    float acc0 = 0.f, acc1 = 0.f;
    int j = 0;
    for (; j + 1 < deg; j += 2) {
        int s0 = csr_src[start + j];
        int s1 = csr_src[start + j + 1];
        float e0, e1;
        if (j < MAXD)     e0 = wbuf[wv][j * 4 + head];
        else { float4 a = als4[s0];
               float ah = (head & 2) ? ((head & 1) ? a.w : a.z) : ((head & 1) ? a.y : a.x);
               float dh = (head & 2) ? ((head & 1) ? aldd.w : aldd.z) : ((head & 1) ? aldd.y : aldd.x);
               e0 = __expf(leaky(ah + dh) - m_h); }
        if (j + 1 < MAXD) e1 = wbuf[wv][(j + 1) * 4 + head];
        else { float4 a = als4[s1];
               float ah = (head & 2) ? ((head & 1) ? a.w : a.z) : ((head & 1) ? a.y : a.x);
               float dh = (head & 2) ? ((head & 1) ? aldd.w : aldd.z) : ((head & 1) ? aldd.y : aldd.x);
               e1 = __expf(leaky(ah + dh) - m_h); }
        float w0 = e0 * inv_h, w1 = e1 * inv_h;
        unsigned hv0 = *(const unsigned*)(h1b + ((size_t)s0 << 7) + 2 * lane);
        unsigned hv1 = *(const unsigned*)(h1b + ((size_t)s1 << 7) + 2 * lane);
        acc0 += __uint_as_float(hv0 << 16)          * w0;
        acc1 += __uint_as_float(hv0 & 0xffff0000u)  * w0;
        acc0 += __uint_as_float(hv1 << 16)          * w1;
        acc1 += __uint_as_float(hv1 & 0xffff0000u)  * w1;
    }
    if (j < deg) {
        int s0 = csr_src[start + j];
        float e0;
        if (j < MAXD) e0 = wbuf[wv][j * 4 + head];
        else { float4 a = als4[s0];
               float ah = (head & 2) ? ((head & 1) ? a.w : a.z) : ((head & 1) ? a.y : a.x);
               float dh = (head & 2) ? ((head & 1) ? aldd.w : aldd.z) : ((head & 1) ? aldd.y : aldd.x);
               e0 = __expf(leaky(ah + dh) - m_h); }
        float w0 = e0 * inv_h;
        unsigned hv0 = *(const unsigned*)(h1b + ((size_t)s0 << 7) + 2 * lane);
        acc0 += __uint_as_float(hv0 << 16)         * w0;
        acc1 += __uint_as_float(hv0 & 0xffff0000u) * w0;
    }
    float v0 = acc0 + b1[2 * lane];
    float v1 = acc1 + b1[2 * lane + 1];
    v0 = v0 > 0.f ? v0 : __expf(v0) - 1.f;
    v1 = v1 > 0.f ? v1 : __expf(v1) - 1.f;
    float2 o = make_float2(v0, v1);
    *(float2*)&out1[(size_t)d * 128 + 2 * lane] = o;
}

// ===== layer2 fused: per-dst softmax (LDS weights) + bf16 gather + bias =====
// pass B: 3 edge-slots x 20 channel-pair lanes (60/64 active), cross-slot shfl reduce
__global__ __launch_bounds__(256) void agg2_kernel(const int* __restrict__ row,
                                                   const int* __restrict__ csr_src,
                                                   const float* __restrict__ als,
                                                   const float* __restrict__ ald,
                                                   const unsigned short* __restrict__ h2b,
                                                   const float* __restrict__ b2,
                                                   float* __restrict__ out) {
    __shared__ float wbuf[4][MAXD];
    int wv   = threadIdx.x >> 6;
    int lane = threadIdx.x & 63;
    int d    = blockIdx.x * 4 + wv;
    int start = row[d], end = row[d + 1], deg = end - start;
    float aldd = ald[d];

    float mx = NEG_INF;
    for (int j = lane; j < deg; j += 64) {
        int s = csr_src[start + j];
        float a = leaky(als[s] + aldd);
        if (j < MAXD) wbuf[wv][j] = a;
        mx = fmaxf(mx, a);
    }
    #pragma unroll
    for (int off = 32; off >= 1; off >>= 1) mx = fmaxf(mx, __shfl_xor(mx, off));
    __syncthreads();

    float sm = 0.f;
    for (int j = lane; j < deg; j += 64) {
        float a;
        if (j < MAXD) a = wbuf[wv][j];
        else { int s = csr_src[start + j]; a = leaky(als[s] + aldd); }
        float e = __expf(a - mx);
        if (j < MAXD) wbuf[wv][j] = e;
        sm += e;
    }
    #pragma unroll
    for (int off = 32; off >= 1; off >>= 1) sm += __shfl_xor(sm, off);
    __syncthreads();
    float inv = 1.f / (sm + 1e-16f);

    int slot = lane / 20;              // 0..2 active, 3 idle
    int idx  = lane - slot * 20;       // channel pair 0..19
    float acc0 = 0.f, acc1 = 0.f;
    int j0 = (lane < 60) ? slot : deg;
    for (int j = j0; j < deg; j += 3) {
        int s = csr_src[start + j];
        float e;
        if (j < MAXD) e = wbuf[wv][j];
        else          e = __expf(leaky(als[s] + aldd) - mx);
        float w = e * inv;
        unsigned hv = *(const unsigned*)(h2b + (size_t)s * 40 + 2 * idx);
        acc0 += __uint_as_float(hv << 16)         * w;
        acc1 += __uint_as_float(hv & 0xffff0000u) * w;
    }
    // reduce across the 3 slots: lanes idx, idx+20, idx+40
    float t0 = __shfl(acc0, idx + 20), u0 = __shfl(acc1, idx + 20);
    float t1 = __shfl(acc0, idx + 40), u1 = __shfl(acc1, idx + 40);
    acc0 += t0 + t1; acc1 += u0 + u1;
    if (lane < 20) {
        float2 o = make_float2(acc0 + b2[2 * lane], acc1 + b2[2 * lane + 1]);
        *(float2*)&out[(size_t)d * 40 + 2 * lane] = o;
    }
}

// ===== GEMM2: h2b[N,40] bf16 = out1[N,128] @ W2[128,40]; 64 rows/block, 2x4 per thread =====
__global__ __launch_bounds__(320) void gemm2_kernel(const float* __restrict__ x,
                                                    const float* __restrict__ W,
                                                    unsigned short* __restrict__ h2b) {
    __shared__ float wS[128 * 40];    // 20 KB
    __shared__ float xS[64 * 129];    // 33 KB (+1 pad: distinct banks across rows)
    int t = threadIdx.x;
    int row0 = blockIdx.x * 64;
    for (int i = t; i < 128 * 40; i += 320) wS[i] = W[i];
    for (int fi = t; fi < 2048; fi += 320) {
        int r = fi >> 5, c4 = (fi & 31) * 4;
        int gr = row0 + r;
        float4 v = make_float4(0.f, 0.f, 0.f, 0.f);
        if (gr < N_NODES) v = *(const float4*)&x[(size_t)gr * 128 + c4];
        xS[r * 129 + c4 + 0] = v.x; xS[r * 129 + c4 + 1] = v.y;
        xS[r * 129 + c4 + 2] = v.z; xS[r * 129 + c4 + 3] = v.w;
    }
    __syncthreads();
    int cp = t % 20;        // col pair -> cols {2cp, 2cp+1}
    int rg = t / 20;        // 0..15 -> rows rg*4..rg*4+3
    float acc[4][2] = {{0.f,0.f},{0.f,0.f},{0.f,0.f},{0.f,0.f}};
    for (int k = 0; k < 128; ++k) {
        float2 w2 = *(float2*)&wS[k * 40 + 2 * cp];
        #pragma unroll
        for (int r = 0; r < 4; ++r) {
            float xv = xS[(rg * 4 + r) * 129 + k];
            acc[r][0] += xv * w2.x;
            acc[r][1] += xv * w2.y;
        }
    }
    #pragma unroll
    for (int r = 0; r < 4; ++r) {
        int n = row0 + rg * 4 + r;
        if (n < N_NODES) {
            unsigned p = ((unsigned)f2bf(acc[r][1]) << 16) | f2bf(acc[r][0]);
            *(unsigned*)&h2b[(size_t)n * 40 + 2 * cp] = p;
        }
    }
}

// ================= workspace layout (float-sized slots) =================
constexpr size_t OFF_H1B    = 0;          // 3,200,000 slots (bf16 x 6.4M); h2b overlays after agg1
constexpr size_t OFF_OUT1   = 3200000;    // 6,400,000
constexpr size_t OFF_ALS1   = 9600000;    // 200,000 (als2 overlays)
constexpr size_t OFF_ALD1   = 9800000;    // 200,000 (ald2 overlays)
constexpr size_t OFF_ROW    = 10000000;   // 50,001 ints
constexpr size_t OFF_CURSOR = 10060000;   // 50,000 ints
constexpr size_t OFF_DEG    = 10120000;   // 50,000 ints
constexpr size_t OFF_PART   = 10180000;   // 128 ints
constexpr size_t OFF_CSRC   = 10200000;   // 850,000 ints
constexpr size_t WS_FLOATS  = 11050000;   // 44.2 MB

extern "C" void kernel_launch(void* const* d_in, const int* in_sizes, int n_in,
                              void* d_out, int out_size, void* d_ws, size_t ws_size,
                              hipStream_t stream) {
    const float* x   = (const float*)d_in[0];
    const int*   ei  = (const int*)  d_in[1];
    const float* W1  = (const float*)d_in[2];
    const float* as1 = (const float*)d_in[3];
    const float* ad1 = (const float*)d_in[4];
    const float* b1  = (const float*)d_in[5];
    const float* W2  = (const float*)d_in[6];
    const float* as2 = (const float*)d_in[7];
    const float* ad2 = (const float*)d_in[8];
    const float* b2  = (const float*)d_in[9];
    float* out = (float*)d_out;

    if (ws_size < WS_FLOATS * sizeof(float)) return;

    float* ws = (float*)d_ws;
    unsigned short* h1b = (unsigned short*)(ws + OFF_H1B);
    unsigned short* h2b = (unsigned short*)(ws + OFF_H1B);   // overlay, h1b dead after agg1
    float* out1    = ws + OFF_OUT1;
    float* als1    = ws + OFF_ALS1;
    float* ald1    = ws + OFF_ALD1;
    float* als2    = ws + OFF_ALS1;   // overlay
    float* ald2    = ws + OFF_ALD1;   // overlay
    int*   rowp    = (int*)(ws + OFF_ROW);
    int*   cursor  = (int*)(ws + OFF_CURSOR);
    int*   deg     = (int*)(ws + OFF_DEG);
    int*   part    = (int*)(ws + OFF_PART);
    int*   csr_src = (int*)(ws + OFF_CSRC);

    int egrid = cdiv(ETOT, 256);

    // ---- CSR build (shared by both layers) ----
    hipMemsetAsync(deg, 0, (size_t)N_NODES * sizeof(int), stream);
    deg_count_kernel<<<egrid, 256, 0, stream>>>(ei, deg);
    partial_sum_kernel<<<SCAN_NBLK, 256, 0, stream>>>(deg, part);
    scan_part_kernel<<<1, 64, 0, stream>>>(part);
    chunk_scan_kernel<<<SCAN_NBLK, 256, 0, stream>>>(deg, part, rowp, cursor);
    fill_csr_kernel<<<egrid, 256, 0, stream>>>(ei, cursor, csr_src);

    // ---- layer 1 ----
    gemm1_kernel<<<cdiv(N_NODES, 32), 256, 0, stream>>>(x, W1, as1, ad1, h1b, als1, ald1);
    agg1_kernel<<<N_NODES / 4, 256, 0, stream>>>(rowp, csr_src,
                                                 (const float4*)als1, (const float4*)ald1,
                                                 h1b, b1, out1);

    // ---- layer 2 ----
    gemm2_kernel<<<cdiv(N_NODES, 64), 320, 0, stream>>>(out1, W2, h2b);
    att2_kernel<<<cdiv(N_NODES, 4), 256, 0, stream>>>(h2b, as2, ad2, als2, ald2);
    agg2_kernel<<<N_NODES / 4, 256, 0, stream>>>(rowp, csr_src, als2, ald2, h2b, b2, out);
}